// Round 14
// baseline (182.976 us; speedup 1.0000x reference)
//
#include <hip/hip_runtime.h>
#include <hip/hip_bf16.h>
#include <stdint.h>

typedef __attribute__((ext_vector_type(8))) short short8;
typedef __attribute__((ext_vector_type(4))) short short4v;
typedef __attribute__((ext_vector_type(4))) float f32x4;

#define MFMA(a, b, c) __builtin_amdgcn_mfma_f32_16x16x32_bf16((a), (b), (c), 0, 0, 0)

#define C1 0.18033688011112042f      // 0.125 * log2(e)
#define INV_C1 5.545177444479562f    // 1 / C1

// packed fp32x2 -> bf16x2 (RNE)
static __device__ __forceinline__ unsigned int f2bf2(float x, float y) {
  union { __hip_bfloat162 h; unsigned int u; } c;
  c.h = __float22bfloat162_rn(make_float2(x, y));
  return c.u;
}

// single-instruction HW paths (libm/header versions expand to 6-11 instrs)
static __device__ __forceinline__ float exp2_fast(float x) {
  float r;
  asm("v_exp_f32 %0, %1" : "=v"(r) : "v"(x));
  return r;
}
static __device__ __forceinline__ unsigned int cvtpk(float lo, float hi) {
  unsigned int r;  // dst.lo = bf16(lo), dst.hi = bf16(hi), RNE
  asm("v_cvt_pk_bf16_f32 %0, %1, %2" : "=v"(r) : "v"(lo), "v"(hi));
  return r;
}

// int-ordered max on non-negative floats; ws poison (negative int) = identity
static __device__ __forceinline__ void atomic_max_f32(float* addr, float v) {
  atomicMax((int*)addr, __float_as_int(v));
}

// async global->LDS DMA, 16B per lane; LDS dest is wave-uniform base + lane*16
static __device__ __forceinline__ void gl_lds16(const void* g, void* l) {
  __builtin_amdgcn_global_load_lds(
      (const __attribute__((address_space(1))) void*)g,
      (__attribute__((address_space(3))) void*)l, 16, 0, 0);
}

// ---------------- fp32 -> bf16 conversion INTO PRE-TILED layouts ----------
// Xb: [yb][kk][q][r][j] contiguous 8KB tiles = LDS staging image (r9, kept).
// Wb: [z][colb][kk][q][r][j].
__global__ __launch_bounds__(256) void k_cvt(
    const float* __restrict__ X, const float* __restrict__ Wq,
    const float* __restrict__ Wk, const float* __restrict__ Wv,
    short* __restrict__ Xb, short* __restrict__ Wb) {
  const int y = blockIdx.y;
  const int i = (blockIdx.x * 256 + threadIdx.x) * 8;
  const float* src;
  short* dstbase;
  if (y == 0) {
    if (i >= 4096 * 1024) return;
    src = X;
    dstbase = Xb;
  } else {
    if (i >= 1048576) return;
    src = (y == 1) ? Wq : (y == 2) ? Wk : Wv;
    dstbase = Wb + (y - 1) * 1048576;
  }
  const float4 a = *(const float4*)(src + i);
  const float4 b = *(const float4*)(src + i + 4);
  union { unsigned int u[4]; short8 s; } P;
  P.u[0] = f2bf2(a.x, a.y);
  P.u[1] = f2bf2(a.z, a.w);
  P.u[2] = f2bf2(b.x, b.y);
  P.u[3] = f2bf2(b.z, b.w);
  const int s = i >> 10, c0 = i & 1023;  // source row, col
  const int off = (((s >> 7) * 32 + (c0 >> 5)) * 4 + ((c0 >> 3) & 3)) * 1024 +
                  (s & 127) * 8;
  *(short8*)(dstbase + off) = P.s;
}

// ---------------- QKV projection: Y = X @ W^T + b (bf16 inputs) ------------
// (unchanged from round 12: 3-buffer depth-2 counted-vmcnt pipeline;
// K/V written as pre-tiled+pre-swizzled per-(bh,kt) 8KB frag images)
__global__ __launch_bounds__(256) void k_qkv(
    const short* __restrict__ Xb, const short* __restrict__ Wball,
    const float* __restrict__ bq, const float* __restrict__ bk,
    const float* __restrict__ bv,
    short* __restrict__ Qo, short* __restrict__ Ko, short* __restrict__ Vo,
    float* __restrict__ stats) {
  const int fid = (blockIdx.z * 32 + blockIdx.y) * 8 + blockIdx.x;
  const int sid = (fid & 7) * 96 + (fid >> 3);
  const int colb = sid & 7;   // N-tile 0..7
  const int zy = sid >> 3;    // 0..95
  const int z = zy >> 5;      // 0..2 (Q/K/V)
  const int yb = zy & 31;     // M-tile 0..31

  const float* bias = (z == 0) ? bq : (z == 1) ? bk : bv;
  short* out = (z == 0) ? Qo : (z == 1) ? Ko : Vo;
  const bool qk = (z < 2);

  __shared__ __align__(16) short B0s[8192];  // A=[0,4096) B=[4096,8192)
  __shared__ __align__(16) short B1s[8192];
  __shared__ __align__(16) short B2s[8192];
  __shared__ float red[4];

  const int t = threadIdx.x;
  const int lane = t & 63;
  const int w = t >> 6;
  const int l16 = lane & 15, quad = lane >> 4;
  const int wr = (w >> 1) * 64, wc = (w & 1) * 64;
  const int row0 = yb * 128;
  const int col0 = colb * 128;

  // pre-tiled staging bases: tile(kk) = base + kk*4096 shorts (contiguous)
  const short* ag = Xb + yb * 131072 + w * 512 + lane * 8;
  const short* bg = Wball + z * 1048576 + colb * 131072 + w * 512 + lane * 8;

  // frag bases (z-dependent operand swap): {matbase, rowbase}
  const int f0b = qk ? 4096 : 0, f0r = qk ? wc : wr;
  const int f1b = qk ? 0 : 4096, f1r = qk ? wr : wc;
  const int cq = quad * 1024;  // chunk offset in shorts

  f32x4 acc[4][4];
#pragma unroll
  for (int i = 0; i < 4; ++i)
#pragma unroll
    for (int j = 0; j < 4; ++j) acc[i][j] = {0.f, 0.f, 0.f, 0.f};

#define STAGE(buf, ko_)                                  \
  do {                                                   \
    gl_lds16(ag + (ko_), (buf) + w * 512);               \
    gl_lds16(ag + (ko_) + 2048, (buf) + 2048 + w * 512); \
    gl_lds16(bg + (ko_), (buf) + 4096 + w * 512);        \
    gl_lds16(bg + (ko_) + 2048, (buf) + 6144 + w * 512); \
  } while (0)

#define COMPUTE(buf)                                                   \
  do {                                                                 \
    short8 fr0[4], fr1[4];                                             \
    _Pragma("unroll") for (int a = 0; a < 4; ++a)                      \
        fr0[a] = *(const short8*)&(buf)[f0b + cq + (f0r + a * 16 + l16) * 8]; \
    _Pragma("unroll") for (int b = 0; b < 4; ++b)                      \
        fr1[b] = *(const short8*)&(buf)[f1b + cq + (f1r + b * 16 + l16) * 8]; \
    _Pragma("unroll") for (int a = 0; a < 4; ++a)                      \
        _Pragma("unroll") for (int b = 0; b < 4; ++b)                  \
            acc[a][b] = MFMA(fr0[a], fr1[b], acc[a][b]);               \
  } while (0)

// counted barrier: all ds_reads serviced + all but newest N gl_lds landed
#define WAITBAR(n)                                                          \
  do {                                                                      \
    asm volatile("s_waitcnt lgkmcnt(0) vmcnt(" #n ")\n\ts_barrier" ::: "memory"); \
    __builtin_amdgcn_sched_barrier(0);                                      \
  } while (0)

  STAGE(B0s, 0);
  STAGE(B1s, 4096);
  WAITBAR(4);   // tile 0 ready; tile 1's 4 loads in flight
  int ks = 8192;  // short-offset of next tile to stage (tile 2)
#pragma unroll
  for (int i = 0; i < 10; ++i) {  // tiles 0..29; stages tiles 2..31
    STAGE(B2s, ks); ks += 4096; COMPUTE(B0s); WAITBAR(4);
    STAGE(B0s, ks); ks += 4096; COMPUTE(B1s); WAITBAR(4);
    STAGE(B1s, ks); ks += 4096; COMPUTE(B2s); WAITBAR(4);
  }
  COMPUTE(B0s);  // tile 30 (ready: last WAITBAR(4) left only tile 31 in flight)
  WAITBAR(0);    // drain tile 31
  COMPUTE(B1s);  // tile 31
#undef STAGE
#undef COMPUTE
#undef WAITBAR

  float amax = 0.f;
  if (z == 0) {
    // Q: acc[a=d-tile][b=s-tile]; packed [bh][s][dh], pre-scaled by C1
#pragma unroll
    for (int a = 0; a < 4; ++a) {
      const int dg = col0 + wc + a * 16 + quad * 4;
      const float4 b4 = *(const float4*)&bias[dg];
      const int h = dg >> 6, dl = dg & 63;
#pragma unroll
      for (int b = 0; b < 4; ++b) {
        const int sg = row0 + wr + b * 16 + l16;
        const float y0 = acc[a][b][0] + b4.x;
        const float y1 = acc[a][b][1] + b4.y;
        const float y2 = acc[a][b][2] + b4.z;
        const float y3 = acc[a][b][3] + b4.w;
        amax = fmaxf(amax, fmaxf(fmaxf(fabsf(y0), fabsf(y1)), fmaxf(fabsf(y2), fabsf(y3))));
        union { unsigned int u[2]; short4v s; } pk;
        pk.u[0] = cvtpk(y0 * C1, y1 * C1);
        pk.u[1] = cvtpk(y2 * C1, y3 * C1);
        const int bidx = sg >> 11, sl = sg & 2047;
        *(short4v*)&out[(size_t)((((bidx << 4) | h) * 2048 + sl)) * 64 + dl] = pk.s;
      }
    }
  } else if (z == 1) {
    // K: tiled+swizzled image; 4 consecutive d (dl&7 in {0,4}) at one s
#pragma unroll
    for (int a = 0; a < 4; ++a) {
      const int dg = col0 + wc + a * 16 + quad * 4;
      const float4 b4 = *(const float4*)&bias[dg];
      const int h = dg >> 6, dl = dg & 63;
#pragma unroll
      for (int b = 0; b < 4; ++b) {
        const int sg = row0 + wr + b * 16 + l16;
        const float y0 = acc[a][b][0] + b4.x;
        const float y1 = acc[a][b][1] + b4.y;
        const float y2 = acc[a][b][2] + b4.z;
        const float y3 = acc[a][b][3] + b4.w;
        amax = fmaxf(amax, fmaxf(fmaxf(fabsf(y0), fabsf(y1)), fmaxf(fabsf(y2), fabsf(y3))));
        union { unsigned int u[2]; short4v s; } pk;
        pk.u[0] = cvtpk(y0, y1);
        pk.u[1] = cvtpk(y2, y3);
        const int bidx = sg >> 11, sl = sg & 2047;
        const int ktt = sl >> 6, row = sl & 63;
        const size_t tb = ((size_t)(((bidx << 4) | h) * 32 + ktt) * 64 + row) * 64;
        *(short4v*)&out[tb + (((dl >> 3) ^ (row & 7)) * 8) + (dl & 7)] = pk.s;
      }
    }
  } else {
    // V: tiled+swizzled image; 4 consecutive keys (key&7 in {0,4}) at one d
#pragma unroll
    for (int a = 0; a < 4; ++a) {
      const int sg = row0 + wr + a * 16 + quad * 4;
      const int bidx = sg >> 11, sl = sg & 2047;
      const int ktt = sl >> 6, key = sl & 63;
#pragma unroll
      for (int b = 0; b < 4; ++b) {
        const int dg = col0 + wc + b * 16 + l16;
        const float bvf = bias[dg];
        const int h = dg >> 6, dl = dg & 63;
        const float y0 = acc[a][b][0] + bvf;
        const float y1 = acc[a][b][1] + bvf;
        const float y2 = acc[a][b][2] + bvf;
        const float y3 = acc[a][b][3] + bvf;
        amax = fmaxf(amax, fmaxf(fmaxf(fabsf(y0), fabsf(y1)), fmaxf(fabsf(y2), fabsf(y3))));
        union { unsigned int u[2]; short4v s; } pk;
        pk.u[0] = cvtpk(y0, y1);
        pk.u[1] = cvtpk(y2, y3);
        const size_t tb = ((size_t)(((bidx << 4) | h) * 32 + ktt) * 64 + dl) * 64;
        *(short4v*)&out[tb + (((key >> 3) ^ (dl & 7)) * 8) + (key & 7)] = pk.s;
      }
    }
  }
#pragma unroll
  for (int off = 32; off > 0; off >>= 1)
    amax = fmaxf(amax, __shfl_xor(amax, off, 64));
  if (lane == 0) red[w] = amax;
  __syncthreads();
  if (t == 0) {
    float m = fmaxf(fmaxf(red[0], red[1]), fmaxf(red[2], red[3]));
    atomic_max_f32(&stats[z], m);  // 0=q,1=k,2=v
  }
}

// ---------------- flash attention: 4w x 32 q-rows, DMA-staged, 2 blk/CU ---
// r13 lesson: 1 block/CU kills the inter-block MFMA||VALU overlap (m114).
// This round: r12's DMA staging + counted vmcnt (proven) with r11's traffic
// cut (32 rows/wave: K/V frags read once, reused for 2 q-groups), at r12's
// 2-blocks/CU co-residency. Block 256 = 4 waves x 32 rows (q-tile 128);
// grid (16,32)=512 = 2/CU; LDS 64KB/block -> both blocks fit.
// LDS/CU-kt: 2 x (stage 16 + Kfrag 32 + Vfrag 32 + Ps 32) = 224 KB (-36%).
// 3-buffer K/V tiles (pre-swizzled images from k_qkv), AWAITBAR(4).
// Q pre-scaled by C1 -> sacc IS the exp2 arg; no-rescale softmax;
// qk_out_max = max(m,-xmin)/C1; O = O'/l at end. XCD swizzle 512 = 8*64.
__global__ __launch_bounds__(256, 2) void k_attn(
    const short* __restrict__ Q, const short* __restrict__ K,
    const short* __restrict__ V, float* __restrict__ O,
    float* __restrict__ stats) {
  const int fid = blockIdx.y * 16 + blockIdx.x;
  const int sid = ((fid & 7) << 6) + (fid >> 3);  // bijective: 512 = 8*64
  const int bh = sid >> 4;
  const int q0 = (sid & 15) << 7;  // q-tile of 128 rows
  const short* Qh = Q + (size_t)bh * 2048 * 64;

  __shared__ __align__(16) short Ks[3 * 4096];   // 3-buffer K tiles (image)
  __shared__ __align__(16) short Vts[3 * 4096];  // 3-buffer V tiles (image)
  __shared__ __align__(16) short Ps[4][32 * 64];  // swizzled, wave-private
  __shared__ float redA[4], redB[4];

  const int t = threadIdx.x, lane = t & 63, w = t >> 6;  // w 0..3
  const int l16 = lane & 15, quad = lane >> 4;
  const int rsw = (l16 & 7);          // read-side row parity bits
  short* myPs = &Ps[w][0];

  // DMA staging bases: tile kt = base + kt*4096 shorts; wave w copies
  // shorts [w*1024, +1024) via 2 calls (lane i: 16B at +lane*8).
  const short* kg = K + (size_t)bh * 131072 + w * 1024 + lane * 8;
  const short* vg = V + (size_t)bh * 131072 + w * 1024 + lane * 8;

  // Q B-frags (loop-invariant): group g q-row = q0 + w*32 + g*16 + l16
  short8 bq8[2][2];
#pragma unroll
  for (int g = 0; g < 2; ++g) {
    const short* qsrc = Qh + (q0 + w * 32 + g * 16 + l16) * 64 + quad * 8;
    bq8[g][0] = *(const short8*)qsrc;
    bq8[g][1] = *(const short8*)(qsrc + 32);
  }

  float m_lane[2] = {-1e30f, -1e30f}, l_lane[2] = {0.f, 0.f};
  float xmin_lane[2] = {1e30f, 1e30f};
  f32x4 o_acc[2][4];
#pragma unroll
  for (int g = 0; g < 2; ++g)
#pragma unroll
    for (int jn = 0; jn < 4; ++jn) o_acc[g][jn] = {0.f, 0.f, 0.f, 0.f};
  const f32x4 zero = {0.f, 0.f, 0.f, 0.f};

  // swizzled read slot offsets (shorts): kf0 slot = quad^rsw, kf1 = that^4
  const int ksl0 = (quad ^ rsw) * 8;
  const int ksl1 = ((quad ^ rsw) ^ 4) * 8;

#define ASTAGE(cb, ko_)                                      \
  do {                                                       \
    gl_lds16(kg + (ko_), Ks + (cb) * 4096 + w * 1024);       \
    gl_lds16(kg + (ko_) + 512, Ks + (cb) * 4096 + w * 1024 + 512); \
    gl_lds16(vg + (ko_), Vts + (cb) * 4096 + w * 1024);      \
    gl_lds16(vg + (ko_) + 512, Vts + (cb) * 4096 + w * 1024 + 512); \
  } while (0)

#define AWAITBAR(n)                                                         \
  do {                                                                      \
    asm volatile("s_waitcnt lgkmcnt(0) vmcnt(" #n ")\n\ts_barrier" ::: "memory"); \
    __builtin_amdgcn_sched_barrier(0);                                      \
  } while (0)

#define ACOMPUTE(cb)                                                        \
  do {                                                                      \
    const int kbase = (cb) * 4096;                                          \
    f32x4 sacc[2][4];                                                       \
    __builtin_amdgcn_s_setprio(1);                                          \
    _Pragma("unroll") for (int j = 0; j < 4; ++j) {                         \
      const int kb = kbase + (j * 16 + l16) * 64;                           \
      short8 kf0 = *(const short8*)&Ks[kb + ksl0];                          \
      short8 kf1 = *(const short8*)&Ks[kb + ksl1];                          \
      sacc[0][j] = MFMA(kf1, bq8[0][1], MFMA(kf0, bq8[0][0], zero));        \
      sacc[1][j] = MFMA(kf1, bq8[1][1], MFMA(kf0, bq8[1][0], zero));        \
    }                                                                       \
    __builtin_amdgcn_s_setprio(0);                                          \
    _Pragma("unroll") for (int g = 0; g < 2; ++g) {                         \
      float pmax = m_lane[g], psum = l_lane[g], xmn = xmin_lane[g];         \
      _Pragma("unroll") for (int j = 0; j < 4; ++j) {                       \
        const float x0 = sacc[g][j][0], x1 = sacc[g][j][1];                 \
        const float x2 = sacc[g][j][2], x3 = sacc[g][j][3];                 \
        pmax = fmaxf(fmaxf(x0, fmaxf(x1, x2)), fmaxf(x3, pmax));            \
        xmn = fminf(fminf(x0, fminf(x1, x2)), fminf(x3, xmn));              \
        const float e0 = exp2_fast(x0), e1 = exp2_fast(x1);                 \
        const float e2 = exp2_fast(x2), e3 = exp2_fast(x3);                 \
        psum += (e0 + e1) + (e2 + e3);                                      \
        union { unsigned int u[2]; short4v s; } pk;                         \
        pk.u[0] = cvtpk(e0, e1);                                            \
        pk.u[1] = cvtpk(e2, e3);                                            \
        *(short4v*)&myPs[(g * 16 + l16) * 64 +                              \
                         ((j * 16 + quad * 4) ^ (rsw << 3))] = pk.s;        \
      }                                                                     \
      m_lane[g] = pmax; l_lane[g] = psum; xmin_lane[g] = xmn;               \
    }                                                                       \
    asm volatile("" ::: "memory");                                          \
    __builtin_amdgcn_s_setprio(1);                                          \
    _Pragma("unroll") for (int tstep = 0; tstep < 2; ++tstep) {             \
      const int psl = (tstep * 32 + quad * 8) ^ (rsw << 3);                 \
      short8 ap0 = *(const short8*)&myPs[l16 * 64 + psl];                   \
      short8 ap1 = *(const short8*)&myPs[(16 + l16) * 64 + psl];            \
      _Pragma("unroll") for (int jn = 0; jn < 4; ++jn) {                    \
        short8 vf = *(const short8*)&Vts[kbase + (jn * 16 + l16) * 64 + psl]; \
        o_acc[0][jn] = MFMA(ap0, vf, o_acc[0][jn]);                         \
        o_acc[1][jn] = MFMA(ap1, vf, o_acc[1][jn]);                         \
      }                                                                     \
    }                                                                       \
    __builtin_amdgcn_s_setprio(0);                                          \
    asm volatile("" ::: "memory");                                          \
  } while (0)

  ASTAGE(0, 0);
  ASTAGE(1, 4096);
  AWAITBAR(4);  // tile 0 landed; tile 1's 4 loads in flight
  int ko = 8192;  // short-offset of next tile to stage (tile 2)
#pragma unroll
  for (int i = 0; i < 10; ++i) {  // computes tiles 0..29; stages 2..31
    ASTAGE(2, ko); ko += 4096; ACOMPUTE(0); AWAITBAR(4);
    ASTAGE(0, ko); ko += 4096; ACOMPUTE(1); AWAITBAR(4);
    ASTAGE(1, ko); ko += 4096; ACOMPUTE(2); AWAITBAR(4);
  }
  ACOMPUTE(0);  // tile 30
  AWAITBAR(0);  // drain tile 31
  ACOMPUTE(1);  // tile 31
#undef ASTAGE
#undef AWAITBAR
#undef ACOMPUTE

  // cross-quad reductions (row r lives at lanes l16=r, all quads)
  float l_full[2], m_full[2], xm_full[2];
#pragma unroll
  for (int g = 0; g < 2; ++g) {
    float l = l_lane[g];
    l += __shfl_xor(l, 16, 64);
    l += __shfl_xor(l, 32, 64);
    l_full[g] = l;
    float m = m_lane[g];
    m = fmaxf(m, __shfl_xor(m, 16, 64));
    m = fmaxf(m, __shfl_xor(m, 32, 64));
    m_full[g] = m;
    float xm = xmin_lane[g];
    xm = fminf(xm, __shfl_xor(xm, 16, 64));
    xm = fminf(xm, __shfl_xor(xm, 32, 64));
    xm_full[g] = xm;
  }
  float aw = fmaxf(exp2_fast(m_full[0]) / l_full[0],
                   exp2_fast(m_full[1]) / l_full[1]);
  float qkx = fmaxf(fmaxf(m_full[0], -xm_full[0]),
                    fmaxf(m_full[1], -xm_full[1]));  // x-units; /C1 at end

  // write O = O'/l (FP32) to [B,S,H*DH]
  const int bidx = bh >> 4, h = bh & 15;
#pragma unroll
  for (int g = 0; g < 2; ++g) {
    float linv[4];
#pragma unroll
    for (int r = 0; r < 4; ++r)
      linv[r] = 1.0f / __shfl(l_full[g], quad * 4 + r, 16);
#pragma unroll
    for (int jn = 0; jn < 4; ++jn) {
      const int d = jn * 16 + l16;
#pragma unroll
      for (int r = 0; r < 4; ++r) {
        const int s_row = q0 + w * 32 + g * 16 + quad * 4 + r;
        O[((size_t)(bidx * 2048 + s_row) * 1024) + h * 64 + d] =
            o_acc[g][jn][r] * linv[r];
      }
    }
  }

#pragma unroll
  for (int off = 32; off > 0; off >>= 1) {
    qkx = fmaxf(qkx, __shfl_xor(qkx, off, 64));
    aw = fmaxf(aw, __shfl_xor(aw, off, 64));
  }
  if (lane == 0) {
    redA[w] = qkx;
    redB[w] = aw;
  }
  __syncthreads();
  if (t == 0) {
    float a = fmaxf(fmaxf(redA[0], redA[1]), fmaxf(redA[2], redA[3]));
    float b = fmaxf(fmaxf(redB[0], redB[1]), fmaxf(redB[2], redB[3]));
    atomic_max_f32(&stats[3], a * INV_C1);
    atomic_max_f32(&stats[4], b);
  }
}

// ---------------- finalize 6 scalar outputs (FP32) ----------------
// order: q_max, kT_max, qk_out_max, aw_max, v_max, v_out_max(=aw_max)
__global__ void k_fin(const float* __restrict__ stats, float* __restrict__ out) {
  const int i = threadIdx.x;
  if (i == 0) out[0] = stats[0];
  if (i == 1) out[1] = stats[1];
  if (i == 2) out[2] = stats[3];
  if (i == 3) out[3] = stats[4];
  if (i == 4) out[4] = stats[2];
  if (i == 5) out[5] = stats[4];
}

extern "C" void kernel_launch(void* const* d_in, const int* in_sizes, int n_in,
                              void* d_out, int out_size, void* d_ws, size_t ws_size,
                              hipStream_t stream) {
  const float* X = (const float*)d_in[0];
  const float* Wq = (const float*)d_in[1];
  const float* bq = (const float*)d_in[2];
  const float* Wk = (const float*)d_in[3];
  const float* bk = (const float*)d_in[4];
  const float* Wv = (const float*)d_in[5];
  const float* bv = (const float*)d_in[6];
  float* out = (float*)d_out;

  float* stats = (float*)d_ws;  // 8 floats; poison = atomicMax identity
  short* base = (short*)((char*)d_ws + 4096);
  short* Qb = base;                  // 4096*1024  [bh][s][dh]
  short* Kb = base + 4194304;        // 4096*1024  [bh][kt] tiled image
  short* Vb = base + 8388608;        // 4096*1024  [bh][kt] tiled image
  short* Xb = base + 12582912;       // 4096*1024 (pre-tiled)
  short* Wb = base + 16777216;       // 3 * 1024*1024 (pre-tiled)

  k_cvt<<<dim3(2048, 4), 256, 0, stream>>>(X, Wq, Wk, Wv, Xb, Wb);
  k_qkv<<<dim3(8, 32, 3), 256, 0, stream>>>(Xb, Wb, bq, bk, bv, Qb, Kb, Vb, stats);
  k_attn<<<dim3(16, 32), 256, 0, stream>>>(Qb, Kb, Vb, out, stats);
  k_fin<<<1, 64, 0, stream>>>(stats, out + 4194304);
}

// Round 15
// 173.389 us; speedup vs baseline: 1.0553x; 1.0553x over previous
//
#include <hip/hip_runtime.h>
#include <hip/hip_bf16.h>
#include <stdint.h>

typedef __attribute__((ext_vector_type(8))) short short8;
typedef __attribute__((ext_vector_type(4))) short short4v;
typedef __attribute__((ext_vector_type(4))) float f32x4;

#define MFMA(a, b, c) __builtin_amdgcn_mfma_f32_16x16x32_bf16((a), (b), (c), 0, 0, 0)

#define C1 0.18033688011112042f      // 0.125 * log2(e)
#define INV_C1 5.545177444479562f    // 1 / C1

// packed fp32x2 -> bf16x2 (RNE)
static __device__ __forceinline__ unsigned int f2bf2(float x, float y) {
  union { __hip_bfloat162 h; unsigned int u; } c;
  c.h = __float22bfloat162_rn(make_float2(x, y));
  return c.u;
}

// single-instruction HW paths (libm/header versions expand to 6-11 instrs)
static __device__ __forceinline__ float exp2_fast(float x) {
  float r;
  asm("v_exp_f32 %0, %1" : "=v"(r) : "v"(x));
  return r;
}
static __device__ __forceinline__ unsigned int cvtpk(float lo, float hi) {
  unsigned int r;  // dst.lo = bf16(lo), dst.hi = bf16(hi), RNE
  asm("v_cvt_pk_bf16_f32 %0, %1, %2" : "=v"(r) : "v"(lo), "v"(hi));
  return r;
}

// int-ordered max on non-negative floats; ws poison (negative int) = identity
static __device__ __forceinline__ void atomic_max_f32(float* addr, float v) {
  atomicMax((int*)addr, __float_as_int(v));
}

// async global->LDS DMA, 16B per lane; LDS dest is wave-uniform base + lane*16
static __device__ __forceinline__ void gl_lds16(const void* g, void* l) {
  __builtin_amdgcn_global_load_lds(
      (const __attribute__((address_space(1))) void*)g,
      (__attribute__((address_space(3))) void*)l, 16, 0, 0);
}

// ---------------- fp32 -> bf16 conversion INTO PRE-TILED layouts ----------
// LDS-TILED rewrite: the r9+ version wrote 16B at 2KB stride (64 lines per
// store instr -- the same VMEM-transaction bug fixed in k_qkv r8->r9).
// Now: 1 block per 8KB dst tile (grid 1792 = 1024 X + 768 W tiles).
// Read coalesced (thread = 16 consecutive f32 of one row; a row-pair covers
// whole 128B lines), convert, build tile image [q][r][j] in LDS, barrier,
// write the 8KB tile FULLY CONTIGUOUS (32B/thread).
// Xb tile(yb,kk) = Xb + (yb*32+kk)*4096; Wb tile(z,colb,kk) likewise.
__global__ __launch_bounds__(256) void k_cvt(
    const float* __restrict__ X, const float* __restrict__ Wq,
    const float* __restrict__ Wk, const float* __restrict__ Wv,
    short* __restrict__ Xb, short* __restrict__ Wb) {
  const int bid = blockIdx.x;
  const int t = threadIdx.x;
  const float* src;
  short* dst;
  int rowbase, colbase;
  if (bid < 1024) {
    src = X;
    dst = Xb + bid * 4096;
    rowbase = (bid >> 5) * 128;
    colbase = (bid & 31) * 32;
  } else {
    const int widx = bid - 1024;
    const int z = widx >> 8, within = widx & 255;
    src = (z == 0) ? Wq : (z == 1) ? Wk : Wv;
    dst = Wb + widx * 4096;
    rowbase = (within >> 5) * 128;
    colbase = (within & 31) * 32;
  }
  __shared__ __align__(16) short img[4096];
  const int rr = t >> 1, ch = t & 1;  // row 0..127, 16-col half 0/1
  const float* s0 = src + (size_t)(rowbase + rr) * 1024 + colbase + ch * 16;
  const float4 a = *(const float4*)(s0);
  const float4 b = *(const float4*)(s0 + 4);
  const float4 c = *(const float4*)(s0 + 8);
  const float4 d = *(const float4*)(s0 + 12);
  union { unsigned int u[4]; short8 s; } P0, P1;
  P0.u[0] = f2bf2(a.x, a.y);
  P0.u[1] = f2bf2(a.z, a.w);
  P0.u[2] = f2bf2(b.x, b.y);
  P0.u[3] = f2bf2(b.z, b.w);
  P1.u[0] = f2bf2(c.x, c.y);
  P1.u[1] = f2bf2(c.z, c.w);
  P1.u[2] = f2bf2(d.x, d.y);
  P1.u[3] = f2bf2(d.z, d.w);
  *(short8*)&img[(2 * ch) * 1024 + rr * 8] = P0.s;       // q = 2ch
  *(short8*)&img[(2 * ch + 1) * 1024 + rr * 8] = P1.s;   // q = 2ch+1
  __syncthreads();
  *(short8*)&dst[t * 16] = *(const short8*)&img[t * 16];
  *(short8*)&dst[t * 16 + 8] = *(const short8*)&img[t * 16 + 8];
}

// ---------------- QKV projection: Y = X @ W^T + b (bf16 inputs) ------------
// (unchanged from round 12: 3-buffer depth-2 counted-vmcnt pipeline;
// K/V written as pre-tiled+pre-swizzled per-(bh,kt) 8KB frag images)
__global__ __launch_bounds__(256) void k_qkv(
    const short* __restrict__ Xb, const short* __restrict__ Wball,
    const float* __restrict__ bq, const float* __restrict__ bk,
    const float* __restrict__ bv,
    short* __restrict__ Qo, short* __restrict__ Ko, short* __restrict__ Vo,
    float* __restrict__ stats) {
  const int fid = (blockIdx.z * 32 + blockIdx.y) * 8 + blockIdx.x;
  const int sid = (fid & 7) * 96 + (fid >> 3);
  const int colb = sid & 7;   // N-tile 0..7
  const int zy = sid >> 3;    // 0..95
  const int z = zy >> 5;      // 0..2 (Q/K/V)
  const int yb = zy & 31;     // M-tile 0..31

  const float* bias = (z == 0) ? bq : (z == 1) ? bk : bv;
  short* out = (z == 0) ? Qo : (z == 1) ? Ko : Vo;
  const bool qk = (z < 2);

  __shared__ __align__(16) short B0s[8192];  // A=[0,4096) B=[4096,8192)
  __shared__ __align__(16) short B1s[8192];
  __shared__ __align__(16) short B2s[8192];
  __shared__ float red[4];

  const int t = threadIdx.x;
  const int lane = t & 63;
  const int w = t >> 6;
  const int l16 = lane & 15, quad = lane >> 4;
  const int wr = (w >> 1) * 64, wc = (w & 1) * 64;
  const int row0 = yb * 128;
  const int col0 = colb * 128;

  // pre-tiled staging bases: tile(kk) = base + kk*4096 shorts (contiguous)
  const short* ag = Xb + yb * 131072 + w * 512 + lane * 8;
  const short* bg = Wball + z * 1048576 + colb * 131072 + w * 512 + lane * 8;

  // frag bases (z-dependent operand swap): {matbase, rowbase}
  const int f0b = qk ? 4096 : 0, f0r = qk ? wc : wr;
  const int f1b = qk ? 0 : 4096, f1r = qk ? wr : wc;
  const int cq = quad * 1024;  // chunk offset in shorts

  f32x4 acc[4][4];
#pragma unroll
  for (int i = 0; i < 4; ++i)
#pragma unroll
    for (int j = 0; j < 4; ++j) acc[i][j] = {0.f, 0.f, 0.f, 0.f};

#define STAGE(buf, ko_)                                  \
  do {                                                   \
    gl_lds16(ag + (ko_), (buf) + w * 512);               \
    gl_lds16(ag + (ko_) + 2048, (buf) + 2048 + w * 512); \
    gl_lds16(bg + (ko_), (buf) + 4096 + w * 512);        \
    gl_lds16(bg + (ko_) + 2048, (buf) + 6144 + w * 512); \
  } while (0)

#define COMPUTE(buf)                                                   \
  do {                                                                 \
    short8 fr0[4], fr1[4];                                             \
    _Pragma("unroll") for (int a = 0; a < 4; ++a)                      \
        fr0[a] = *(const short8*)&(buf)[f0b + cq + (f0r + a * 16 + l16) * 8]; \
    _Pragma("unroll") for (int b = 0; b < 4; ++b)                      \
        fr1[b] = *(const short8*)&(buf)[f1b + cq + (f1r + b * 16 + l16) * 8]; \
    _Pragma("unroll") for (int a = 0; a < 4; ++a)                      \
        _Pragma("unroll") for (int b = 0; b < 4; ++b)                  \
            acc[a][b] = MFMA(fr0[a], fr1[b], acc[a][b]);               \
  } while (0)

// counted barrier: all ds_reads serviced + all but newest N gl_lds landed
#define WAITBAR(n)                                                          \
  do {                                                                      \
    asm volatile("s_waitcnt lgkmcnt(0) vmcnt(" #n ")\n\ts_barrier" ::: "memory"); \
    __builtin_amdgcn_sched_barrier(0);                                      \
  } while (0)

  STAGE(B0s, 0);
  STAGE(B1s, 4096);
  WAITBAR(4);   // tile 0 ready; tile 1's 4 loads in flight
  int ks = 8192;  // short-offset of next tile to stage (tile 2)
#pragma unroll
  for (int i = 0; i < 10; ++i) {  // tiles 0..29; stages tiles 2..31
    STAGE(B2s, ks); ks += 4096; COMPUTE(B0s); WAITBAR(4);
    STAGE(B0s, ks); ks += 4096; COMPUTE(B1s); WAITBAR(4);
    STAGE(B1s, ks); ks += 4096; COMPUTE(B2s); WAITBAR(4);
  }
  COMPUTE(B0s);  // tile 30 (ready: last WAITBAR(4) left only tile 31 in flight)
  WAITBAR(0);    // drain tile 31
  COMPUTE(B1s);  // tile 31
#undef STAGE
#undef COMPUTE
#undef WAITBAR

  float amax = 0.f;
  if (z == 0) {
    // Q: acc[a=d-tile][b=s-tile]; packed [bh][s][dh], pre-scaled by C1
#pragma unroll
    for (int a = 0; a < 4; ++a) {
      const int dg = col0 + wc + a * 16 + quad * 4;
      const float4 b4 = *(const float4*)&bias[dg];
      const int h = dg >> 6, dl = dg & 63;
#pragma unroll
      for (int b = 0; b < 4; ++b) {
        const int sg = row0 + wr + b * 16 + l16;
        const float y0 = acc[a][b][0] + b4.x;
        const float y1 = acc[a][b][1] + b4.y;
        const float y2 = acc[a][b][2] + b4.z;
        const float y3 = acc[a][b][3] + b4.w;
        amax = fmaxf(amax, fmaxf(fmaxf(fabsf(y0), fabsf(y1)), fmaxf(fabsf(y2), fabsf(y3))));
        union { unsigned int u[2]; short4v s; } pk;
        pk.u[0] = cvtpk(y0 * C1, y1 * C1);
        pk.u[1] = cvtpk(y2 * C1, y3 * C1);
        const int bidx = sg >> 11, sl = sg & 2047;
        *(short4v*)&out[(size_t)((((bidx << 4) | h) * 2048 + sl)) * 64 + dl] = pk.s;
      }
    }
  } else if (z == 1) {
    // K: tiled+swizzled image; 4 consecutive d (dl&7 in {0,4}) at one s
#pragma unroll
    for (int a = 0; a < 4; ++a) {
      const int dg = col0 + wc + a * 16 + quad * 4;
      const float4 b4 = *(const float4*)&bias[dg];
      const int h = dg >> 6, dl = dg & 63;
#pragma unroll
      for (int b = 0; b < 4; ++b) {
        const int sg = row0 + wr + b * 16 + l16;
        const float y0 = acc[a][b][0] + b4.x;
        const float y1 = acc[a][b][1] + b4.y;
        const float y2 = acc[a][b][2] + b4.z;
        const float y3 = acc[a][b][3] + b4.w;
        amax = fmaxf(amax, fmaxf(fmaxf(fabsf(y0), fabsf(y1)), fmaxf(fabsf(y2), fabsf(y3))));
        union { unsigned int u[2]; short4v s; } pk;
        pk.u[0] = cvtpk(y0, y1);
        pk.u[1] = cvtpk(y2, y3);
        const int bidx = sg >> 11, sl = sg & 2047;
        const int ktt = sl >> 6, row = sl & 63;
        const size_t tb = ((size_t)(((bidx << 4) | h) * 32 + ktt) * 64 + row) * 64;
        *(short4v*)&out[tb + (((dl >> 3) ^ (row & 7)) * 8) + (dl & 7)] = pk.s;
      }
    }
  } else {
    // V: tiled+swizzled image; 4 consecutive keys (key&7 in {0,4}) at one d
#pragma unroll
    for (int a = 0; a < 4; ++a) {
      const int sg = row0 + wr + a * 16 + quad * 4;
      const int bidx = sg >> 11, sl = sg & 2047;
      const int ktt = sl >> 6, key = sl & 63;
#pragma unroll
      for (int b = 0; b < 4; ++b) {
        const int dg = col0 + wc + b * 16 + l16;
        const float bvf = bias[dg];
        const int h = dg >> 6, dl = dg & 63;
        const float y0 = acc[a][b][0] + bvf;
        const float y1 = acc[a][b][1] + bvf;
        const float y2 = acc[a][b][2] + bvf;
        const float y3 = acc[a][b][3] + bvf;
        amax = fmaxf(amax, fmaxf(fmaxf(fabsf(y0), fabsf(y1)), fmaxf(fabsf(y2), fabsf(y3))));
        union { unsigned int u[2]; short4v s; } pk;
        pk.u[0] = cvtpk(y0, y1);
        pk.u[1] = cvtpk(y2, y3);
        const size_t tb = ((size_t)(((bidx << 4) | h) * 32 + ktt) * 64 + dl) * 64;
        *(short4v*)&out[tb + (((key >> 3) ^ (dl & 7)) * 8) + (key & 7)] = pk.s;
      }
    }
  }
#pragma unroll
  for (int off = 32; off > 0; off >>= 1)
    amax = fmaxf(amax, __shfl_xor(amax, off, 64));
  if (lane == 0) red[w] = amax;
  __syncthreads();
  if (t == 0) {
    float m = fmaxf(fmaxf(red[0], red[1]), fmaxf(red[2], red[3]));
    atomic_max_f32(&stats[z], m);  // 0=q,1=k,2=v
  }
}

// ---------------- flash attention: 8w x 16 rows, DMA-staged K/V ----------
// (reverted to round-12 exact version -- proven 58.9us; the 8-waves/CU
// variants r11/r13/r14 all regressed: 16 waves/CU TLP beats traffic cuts)
__global__ __launch_bounds__(512) void k_attn(
    const short* __restrict__ Q, const short* __restrict__ K,
    const short* __restrict__ V, float* __restrict__ O,
    float* __restrict__ stats) {
  const int fid = blockIdx.y * 16 + blockIdx.x;
  const int sid = ((fid & 7) << 6) + (fid >> 3);  // bijective: 512 = 8*64
  const int bh = sid >> 4;
  const int q0 = (sid & 15) << 7;
  const short* Qh = Q + (size_t)bh * 2048 * 64;

  __shared__ __align__(16) short Ks[3 * 4096];   // 3-buffer K tiles (image)
  __shared__ __align__(16) short Vts[3 * 4096];  // 3-buffer V tiles (image)
  __shared__ __align__(16) short Ps[8][16 * 64];  // swizzled, wave-private
  __shared__ float redA[8], redB[8];

  const int t = threadIdx.x, lane = t & 63, w = t >> 6;  // w 0..7
  const int l16 = lane & 15, quad = lane >> 4;
  const int rsw = (l16 & 7);          // read-side row parity bits
  short* myPs = &Ps[w][0];

  // DMA staging bases: tile kt = base + kt*4096 shorts; wave w copies
  // shorts [w*512, +512) of the tile (lane i: 16B at +lane*8).
  const short* kg = K + (size_t)bh * 131072 + w * 512 + lane * 8;
  const short* vg = V + (size_t)bh * 131072 + w * 512 + lane * 8;

  // Q B-frags (loop-invariant): q-row = q0 + w*16 + l16 (pre-scaled by C1)
  short8 bq0, bq1;
  {
    const short* qsrc = Qh + (q0 + w * 16 + l16) * 64 + quad * 8;
    bq0 = *(const short8*)qsrc;
    bq1 = *(const short8*)(qsrc + 32);
  }

  float m_lane = -1e30f, l_lane = 0.f, xmin_lane = 1e30f;
  f32x4 o_acc[4];
#pragma unroll
  for (int jn = 0; jn < 4; ++jn) o_acc[jn] = {0.f, 0.f, 0.f, 0.f};
  const f32x4 zero = {0.f, 0.f, 0.f, 0.f};

  // swizzled read slot offsets (shorts): kf0 slot = quad^rsw, kf1 = that^4
  const int ksl0 = (quad ^ rsw) * 8;
  const int ksl1 = ((quad ^ rsw) ^ 4) * 8;

#define ASTAGE(cb, ko_)                            \
  do {                                             \
    gl_lds16(kg + (ko_), Ks + (cb) * 4096 + w * 512);  \
    gl_lds16(vg + (ko_), Vts + (cb) * 4096 + w * 512); \
  } while (0)

#define AWAITBAR(n)                                                         \
  do {                                                                      \
    asm volatile("s_waitcnt lgkmcnt(0) vmcnt(" #n ")\n\ts_barrier" ::: "memory"); \
    __builtin_amdgcn_sched_barrier(0);                                      \
  } while (0)

#define ACOMPUTE(cb)                                                        \
  do {                                                                      \
    const int kbase = (cb) * 4096;                                          \
    f32x4 sacc[4];                                                          \
    __builtin_amdgcn_s_setprio(1);                                          \
    _Pragma("unroll") for (int j = 0; j < 4; ++j) {                         \
      const int kb = kbase + (j * 16 + l16) * 64;                           \
      short8 kf0 = *(const short8*)&Ks[kb + ksl0];                          \
      short8 kf1 = *(const short8*)&Ks[kb + ksl1];                          \
      sacc[j] = MFMA(kf1, bq1, MFMA(kf0, bq0, zero));                       \
    }                                                                       \
    __builtin_amdgcn_s_setprio(0);                                          \
    {                                                                       \
      float pmax = m_lane, psum = l_lane, xmn = xmin_lane;                  \
      _Pragma("unroll") for (int j = 0; j < 4; ++j) {                       \
        const float x0 = sacc[j][0], x1 = sacc[j][1];                       \
        const float x2 = sacc[j][2], x3 = sacc[j][3];                       \
        pmax = fmaxf(fmaxf(x0, fmaxf(x1, x2)), fmaxf(x3, pmax));            \
        xmn = fminf(fminf(x0, fminf(x1, x2)), fminf(x3, xmn));              \
        const float e0 = exp2_fast(x0), e1 = exp2_fast(x1);                 \
        const float e2 = exp2_fast(x2), e3 = exp2_fast(x3);                 \
        psum += (e0 + e1) + (e2 + e3);                                      \
        union { unsigned int u[2]; short4v s; } pk;                         \
        pk.u[0] = cvtpk(e0, e1);                                            \
        pk.u[1] = cvtpk(e2, e3);                                            \
        *(short4v*)&myPs[l16 * 64 + ((j * 16 + quad * 4) ^ (rsw << 3))] = pk.s; \
      }                                                                     \
      m_lane = pmax; l_lane = psum; xmin_lane = xmn;                        \
    }                                                                       \
    asm volatile("" ::: "memory");                                          \
    __builtin_amdgcn_s_setprio(1);                                          \
    _Pragma("unroll") for (int tstep = 0; tstep < 2; ++tstep) {             \
      const int psl = (tstep * 32 + quad * 8) ^ (rsw << 3);                 \
      short8 ap = *(const short8*)&myPs[l16 * 64 + psl];                    \
      _Pragma("unroll") for (int jn = 0; jn < 4; ++jn) {                    \
        short8 vf = *(const short8*)&Vts[kbase + (jn * 16 + l16) * 64 + psl]; \
        o_acc[jn] = MFMA(ap, vf, o_acc[jn]);                                \
      }                                                                     \
    }                                                                       \
    __builtin_amdgcn_s_setprio(0);                                          \
    asm volatile("" ::: "memory");                                          \
  } while (0)

  ASTAGE(0, 0);
  ASTAGE(1, 4096);
  AWAITBAR(2);  // tile 0 landed; tile 1's 2 loads in flight
  int ko = 8192;  // short-offset of next tile to stage (tile 2)
#pragma unroll
  for (int i = 0; i < 10; ++i) {  // computes tiles 0..29; stages 2..31
    ASTAGE(2, ko); ko += 4096; ACOMPUTE(0); AWAITBAR(2);
    ASTAGE(0, ko); ko += 4096; ACOMPUTE(1); AWAITBAR(2);
    ASTAGE(1, ko); ko += 4096; ACOMPUTE(2); AWAITBAR(2);
  }
  ACOMPUTE(0);  // tile 30
  AWAITBAR(0);  // drain tile 31
  ACOMPUTE(1);  // tile 31
#undef ASTAGE
#undef AWAITBAR
#undef ACOMPUTE

  // cross-quad reductions (row r lives at lanes l16=r, all quads)
  float l = l_lane;
  l += __shfl_xor(l, 16, 64);
  l += __shfl_xor(l, 32, 64);
  float m = m_lane;
  m = fmaxf(m, __shfl_xor(m, 16, 64));
  m = fmaxf(m, __shfl_xor(m, 32, 64));
  float xm = xmin_lane;
  xm = fminf(xm, __shfl_xor(xm, 16, 64));
  xm = fminf(xm, __shfl_xor(xm, 32, 64));
  float aw = exp2_fast(m) / l;
  float qkx = fmaxf(m, -xm);  // in x-units; /C1 at the very end

  // write O = O'/l (FP32) to [B,S,H*DH]
  const int bidx = bh >> 4, h = bh & 15;
  float linv[4];
#pragma unroll
  for (int r = 0; r < 4; ++r)
    linv[r] = 1.0f / __shfl(l, quad * 4 + r, 16);
#pragma unroll
  for (int jn = 0; jn < 4; ++jn) {
    const int d = jn * 16 + l16;
#pragma unroll
    for (int r = 0; r < 4; ++r) {
      const int s_row = q0 + w * 16 + quad * 4 + r;
      O[((size_t)(bidx * 2048 + s_row) * 1024) + h * 64 + d] =
          o_acc[jn][r] * linv[r];
    }
  }

#pragma unroll
  for (int off = 32; off > 0; off >>= 1) {
    qkx = fmaxf(qkx, __shfl_xor(qkx, off, 64));
    aw = fmaxf(aw, __shfl_xor(aw, off, 64));
  }
  if (lane == 0) {
    redA[w] = qkx;
    redB[w] = aw;
  }
  __syncthreads();
  if (t == 0) {
    float a = redA[0], b = redB[0];
#pragma unroll
    for (int i = 1; i < 8; ++i) {
      a = fmaxf(a, redA[i]);
      b = fmaxf(b, redB[i]);
    }
    atomic_max_f32(&stats[3], a * INV_C1);
    atomic_max_f32(&stats[4], b);
  }
}

// ---------------- finalize 6 scalar outputs (FP32) ----------------
// order: q_max, kT_max, qk_out_max, aw_max, v_max, v_out_max(=aw_max)
__global__ void k_fin(const float* __restrict__ stats, float* __restrict__ out) {
  const int i = threadIdx.x;
  if (i == 0) out[0] = stats[0];
  if (i == 1) out[1] = stats[1];
  if (i == 2) out[2] = stats[3];
  if (i == 3) out[3] = stats[4];
  if (i == 4) out[4] = stats[2];
  if (i == 5) out[5] = stats[4];
}

extern "C" void kernel_launch(void* const* d_in, const int* in_sizes, int n_in,
                              void* d_out, int out_size, void* d_ws, size_t ws_size,
                              hipStream_t stream) {
  const float* X = (const float*)d_in[0];
  const float* Wq = (const float*)d_in[1];
  const float* bq = (const float*)d_in[2];
  const float* Wk = (const float*)d_in[3];
  const float* bk = (const float*)d_in[4];
  const float* Wv = (const float*)d_in[5];
  const float* bv = (const float*)d_in[6];
  float* out = (float*)d_out;

  float* stats = (float*)d_ws;  // 8 floats; poison = atomicMax identity
  short* base = (short*)((char*)d_ws + 4096);
  short* Qb = base;                  // 4096*1024  [bh][s][dh]
  short* Kb = base + 4194304;        // 4096*1024  [bh][kt] tiled image
  short* Vb = base + 8388608;        // 4096*1024  [bh][kt] tiled image
  short* Xb = base + 12582912;       // 4096*1024 (pre-tiled)
  short* Wb = base + 16777216;       // 3 * 1024*1024 (pre-tiled)

  k_cvt<<<dim3(1792), 256, 0, stream>>>(X, Wq, Wk, Wv, Xb, Wb);
  k_qkv<<<dim3(8, 32, 3), 256, 0, stream>>>(Xb, Wb, bq, bk, bv, Qb, Kb, Vb, stats);
  k_attn<<<dim3(16, 32), 512, 0, stream>>>(Qb, Kb, Vb, out, stats);
  k_fin<<<1, 64, 0, stream>>>(stats, out + 4194304);
}